// Round 6
// baseline (321.361 us; speedup 1.0000x reference)
//
#include <hip/hip_runtime.h>

// GRUModule: MLP(64->128->128,ELU) -> xg=W_ih proj -> segment-parallel GRU(H=128) -> W_out head
// B=128, T=1024. All GEMMs via mfma_f32_16x16x32_bf16.
// ws: [xg bf16 [b][t][384]: 100,663,296 B][ys bf16 [t][g][16][128]: 33,554,432 B] = 128 MiB
// ctrl+segs live in d_out (first ~540 KB), overwritten by out_gemm afterwards.
// R6: scan xbuf LDS (49KB) removed -> per-lane register xg loads (12 bf16/step,
//     prefetched 1 step ahead); hl double-buffered -> 1 barrier/step (was 2).

#define T_SZ 1024

typedef __attribute__((ext_vector_type(8))) short short8;
typedef __attribute__((ext_vector_type(4))) float f32x4;
typedef unsigned long long u64;
typedef unsigned int uint32;

__device__ __forceinline__ unsigned short f2b(float f){
  unsigned int u = __builtin_bit_cast(unsigned int, f);
  u += 0x7fffu + ((u >> 16) & 1u);
  return (unsigned short)(u >> 16);
}
__device__ __forceinline__ float b2f(unsigned int hs){
  unsigned int u = hs << 16;
  return __builtin_bit_cast(float, u);
}
__device__ __forceinline__ short8 load_w8(const float* __restrict__ p){
  const float4* q = (const float4*)p;
  float4 u0 = q[0], u1 = q[1];
  short8 v;
  v[0]=(short)f2b(u0.x); v[1]=(short)f2b(u0.y); v[2]=(short)f2b(u0.z); v[3]=(short)f2b(u0.w);
  v[4]=(short)f2b(u1.x); v[5]=(short)f2b(u1.y); v[6]=(short)f2b(u1.z); v[7]=(short)f2b(u1.w);
  return v;
}
__device__ __forceinline__ float elu(float v){ return v > 0.f ? v : __expf(v) - 1.f; }
__device__ __forceinline__ float sigm(float x){ return 1.f / (1.f + __expf(-x)); }
__device__ __forceinline__ float tanh_fast(float x){
  x = fminf(fmaxf(x, -15.f), 15.f);
  float e = __expf(-2.f * x);
  return (1.f - e) / (1.f + e);
}
#define MFMA16(a,b,c) __builtin_amdgcn_mfma_f32_16x16x32_bf16(a, b, c, 0, 0, 0)

// ctrl layout in d_out (as uint32*): [1]=n_tiles [2]=slot cursor; segs = C+4096

// ---------------------------------------------------------------------------
// seg_build: 16 blocks x 512 thr; block owns 8 batch rows. Enumerate reset-
// delimited segments; reset-started segments are shortened by 1 (step 0 is
// handled elementwise in fused_mlp); counting-sort desc-by-length in LDS;
// reserve 16-aligned global region with ONE atomicAdd; write + len-0 padding.
// ---------------------------------------------------------------------------
__global__ __launch_bounds__(512) void seg_build(const int* __restrict__ ii, uint32* C){
  __shared__ uint32 lh[1024];
  __shared__ uint32 lbase[1024];
  __shared__ uint32 ssum[512];
  __shared__ uint32 sbase;
  uint32* segs = C + 4096;
  const int tid = threadIdx.x;
  const int wv = tid >> 6, lane = tid & 63;
  const int b = blockIdx.x*8 + wv;

  for(int i = tid; i < 1024; i += 512) lh[i] = 0u;
  __syncthreads();

  u64 bal[16], mb[16];
  #pragma unroll
  for(int c=0;c<16;c++){
    int t = c*64 + lane;
    int m = ii[b*T_SZ + t];
    mb[c]  = __ballot(m != 0);
    bal[c] = __ballot((m != 0) || (t == 0));
  }
  int fsA[16]; int nx = T_SZ;
  #pragma unroll
  for(int c=15;c>=0;c--){ fsA[c]=nx; if(bal[c]) nx = c*64 + __builtin_ctzll(bal[c]); }

  int lenA[16], tA[16], rkA[16];
  #pragma unroll
  for(int c=0;c<16;c++){
    lenA[c] = 0;
    if((bal[c] >> lane) & 1ull){
      int t = c*64 + lane;
      u64 hi = (lane < 63) ? (bal[c] >> (lane+1)) : 0ull;
      int nxt = hi ? (t + 1 + __builtin_ctzll(hi)) : fsA[c];
      int len = nxt - t;
      int rst = (int)((mb[c] >> lane) & 1ull);
      len -= rst; t += rst;
      if(len > 0){
        lenA[c] = len; tA[c] = t;
        rkA[c] = (int)atomicAdd(&lh[1024 - len], 1u);
      }
    }
  }
  __syncthreads();

  uint32 c0 = lh[2*tid], c1 = lh[2*tid+1];
  ssum[tid] = c0 + c1;
  __syncthreads();
  #pragma unroll
  for(int off=1; off<512; off<<=1){
    uint32 v = (tid >= off) ? ssum[tid-off] : 0u;
    __syncthreads();
    ssum[tid] += v;
    __syncthreads();
  }
  uint32 excl = tid ? ssum[tid-1] : 0u;
  lbase[2*tid]   = excl;
  lbase[2*tid+1] = excl + c0;
  uint32 total = ssum[511];
  uint32 padded = (total + 15u) & ~15u;
  if(tid == 0){
    sbase = atomicAdd(&C[2], padded);
    atomicAdd(&C[1], padded >> 4);
  }
  __syncthreads();
  const uint32 base = sbase;

  #pragma unroll
  for(int c=0;c<16;c++){
    if(lenA[c] > 0){
      uint32 slot = base + lbase[1024 - lenA[c]] + (uint32)rkA[c];
      segs[slot] = ((uint32)b << 21) | ((uint32)tA[c] << 11) | (uint32)lenA[c];
    }
  }
  for(uint32 i = total + tid; i < padded; i += 512) segs[base + i] = 0u;
}

// ---------------------------------------------------------------------------
// K1: fused MLP1 + MLP2 + W_ih + elementwise reset-step. M=64 tile
// (16 b x 4 t). 8 waves, wave wv owns N-slice n=16wv+col. LDS:
//   xs [4][16][72] (overlaid by xgl [16][388] in G3 phase) | h1 | h2 [4][16][136]
// ---------------------------------------------------------------------------
__global__ __launch_bounds__(512) void fused_mlp(
    const float* __restrict__ x, const int* __restrict__ ii,
    const float* __restrict__ W1, const float* __restrict__ b1,
    const float* __restrict__ W2, const float* __restrict__ b2,
    const float* __restrict__ Wih, const float* __restrict__ bih,
    const float* __restrict__ bhh,
    unsigned short* __restrict__ xg, unsigned short* __restrict__ ys,
    float* __restrict__ hT)
{
  __shared__ __align__(16) char smem[53248];
  unsigned short* xs  = (unsigned short*)smem;            // [4][16][72] = 18432 B
  unsigned short* h1l = (unsigned short*)(smem + 18432);  // [4][16][136] = 17408 B
  unsigned short* h2l = (unsigned short*)(smem + 35840);  // [4][16][136] = 17408 B
  unsigned short* xgl = (unsigned short*)smem;            // [16][388] = 12416 B (overlay)
  __shared__ int iil[64];
  const int tid = threadIdx.x;
  const int wv = tid >> 6, l = tid & 63, quad = l >> 4, col = l & 15;
  const int n = 16*wv + col;

  short8 w1f[2], w2f[4], wif[3][4];
  #pragma unroll
  for(int ks=0; ks<2; ks++) w1f[ks] = load_w8(W1 + n*64  + ks*32 + quad*8);
  #pragma unroll
  for(int ks=0; ks<4; ks++) w2f[ks] = load_w8(W2 + n*128 + ks*32 + quad*8);
  #pragma unroll
  for(int gt=0; gt<3; gt++){
    #pragma unroll
    for(int ks=0; ks<4; ks++)
      wif[gt][ks] = load_w8(Wih + (n + 128*gt)*128 + ks*32 + quad*8);
  }
  const float b1v = b1[n], b2v = b2[n];
  float bihv[3], bhhv[3];
  #pragma unroll
  for(int gt=0; gt<3; gt++){ bihv[gt] = bih[n + 128*gt]; bhhv[gt] = bhh[n + 128*gt]; }

  const int srow = tid >> 5, sk = tid & 31;

  for(int tile = blockIdx.x; tile < 2048; tile += gridDim.x){
    const int g = tile & 7, t0 = (tile >> 3) * 4;
    __syncthreads();
    {
      const float* src = x + (size_t)(16*g + srow)*(T_SZ*64) + (size_t)t0*64;
      #pragma unroll
      for(int j=0; j<2; j++){
        int s = sk + 32*j;
        float4 v = ((const float4*)src)[s];
        int tt = s >> 4, k = (s & 15) * 4;
        unsigned short* dst = xs + (tt*16 + srow)*72 + k;
        dst[0]=f2b(v.x); dst[1]=f2b(v.y); dst[2]=f2b(v.z); dst[3]=f2b(v.w);
      }
    }
    if(tid < 64) iil[tid] = ii[(16*g + (tid & 15))*T_SZ + t0 + (tid >> 4)];
    __syncthreads();
    #pragma unroll
    for(int tt=0; tt<4; tt++){
      f32x4 acc = {b1v, b1v, b1v, b1v};
      #pragma unroll
      for(int ks=0; ks<2; ks++){
        short8 a = *(const short8*)&xs[(tt*16 + col)*72 + ks*32 + quad*8];
        acc = MFMA16(a, w1f[ks], acc);
      }
      #pragma unroll
      for(int r=0; r<4; r++)
        h1l[(tt*16 + quad*4 + r)*136 + n] = f2b(elu(acc[r]));
    }
    __syncthreads();
    #pragma unroll
    for(int tt=0; tt<4; tt++){
      f32x4 acc = {b2v, b2v, b2v, b2v};
      #pragma unroll
      for(int ks=0; ks<4; ks++){
        short8 a = *(const short8*)&h1l[(tt*16 + col)*136 + ks*32 + quad*8];
        acc = MFMA16(a, w2f[ks], acc);
      }
      #pragma unroll
      for(int r=0; r<4; r++)
        h2l[(tt*16 + quad*4 + r)*136 + n] = f2b(elu(acc[r]));
    }
    __syncthreads();
    #pragma unroll
    for(int tt=0; tt<4; tt++){
      f32x4 a0 = {bihv[0], bihv[0], bihv[0], bihv[0]};
      f32x4 a1 = {bihv[1], bihv[1], bihv[1], bihv[1]};
      f32x4 a2 = {bihv[2], bihv[2], bihv[2], bihv[2]};
      #pragma unroll
      for(int ks=0; ks<4; ks++){
        short8 a = *(const short8*)&h2l[(tt*16 + col)*136 + ks*32 + quad*8];
        a0 = MFMA16(a, wif[0][ks], a0);
        a1 = MFMA16(a, wif[1][ks], a1);
        a2 = MFMA16(a, wif[2][ks], a2);
      }
      const int t = t0 + tt;
      #pragma unroll
      for(int r=0; r<4; r++){
        int row = quad*4 + r;
        xgl[row*388 +       n] = f2b(a0[r]);
        xgl[row*388 + 128 + n] = f2b(a1[r]);
        xgl[row*388 + 256 + n] = f2b(a2[r]);
        if(iil[tt*16 + row] != 0){
          float rr = sigm(a0[r] + bhhv[0]);
          float zz = sigm(a1[r] + bhhv[1]);
          float nn = tanh_fast(a2[r] + rr*bhhv[2]);
          float h1 = (1.f - zz)*nn;
          ys[((size_t)(t*8 + g)*16 + row)*128 + n] = f2b(h1);
          if(t == T_SZ-1)
            hT[(16*g + row)*128 + n] = h1;
        }
      }
      __syncthreads();
      {
        unsigned short* dst = xg + ((size_t)(16*g + srow)*T_SZ + t)*384;
        const unsigned short* srcl = xgl + srow*388;
        #pragma unroll
        for(int i=0; i<3; i++)
          *(u64*)(dst + i*128 + sk*4) = *(const u64*)(srcl + i*128 + sk*4);
      }
      if(tt < 3) __syncthreads();
    }
  }
}

// ---------------------------------------------------------------------------
// K2 v3: segment-parallel GRU. One block = tile of 16 segments (sorted desc
// len; padding len=0). Per-lane xg consumption is 12 fixed bf16/step (4 rows x
// 3 gates at nidx) -> direct register loads, prefetched 1 step ahead. h in
// double-buffered LDS (A-layout) -> ONE barrier per step.
// ---------------------------------------------------------------------------
__global__ __launch_bounds__(512) void gru_seg_scan(
    const unsigned short* __restrict__ xg,
    const float* __restrict__ hx,
    const float* __restrict__ Whh, const float* __restrict__ bhh,
    const uint32* __restrict__ C,
    unsigned short* __restrict__ ys, float* __restrict__ hT)
{
  __shared__ unsigned short hl[2][16*136];
  __shared__ int srb[16], srt[16], srlen[16];
  const int tid = threadIdx.x;
  const int wv = tid >> 6, l = tid & 63, quad = l >> 4, col = l & 15;
  const int nidx = 16*wv + col;

  const uint32 ntile = C[1];
  const uint32* segs = C + 4096;

  short8 whf[3][4];
  float bhv[3];
  #pragma unroll
  for(int gt=0; gt<3; gt++){
    int n = nidx + 128*gt;
    bhv[gt] = bhh[n];
    #pragma unroll
    for(int ks=0; ks<4; ks++)
      whf[gt][ks] = load_w8(Whh + n*128 + ks*32 + quad*8);
  }

  for(uint32 tile = blockIdx.x; tile < ntile; tile += gridDim.x){
    __syncthreads();                             // prev tile fully done
    if(tid < 16){
      uint32 w = segs[16*tile + (uint32)tid];
      srb[tid] = (int)(w >> 21);
      srt[tid] = (int)((w >> 11) & 1023u);
      srlen[tid] = (int)(w & 2047u);
    }
    __syncthreads();
    const int maxlen = srlen[0];

    float hreg[4];
    int rl[4];
    size_t xb[4];
    unsigned short xr[4][3];
    #pragma unroll
    for(int r=0; r<4; r++){
      int row = quad*4 + r;
      int b = srb[row], t0 = srt[row];
      rl[r] = srlen[row];
      xb[r] = ((size_t)b*T_SZ + t0)*384 + nidx;
      float h0 = 0.f;
      if(rl[r] > 0){
        h0 = (t0 == 0) ? hx[b*128 + nidx]
                       : b2f(ys[((size_t)((t0-1)*8 + (b>>4))*16 + (b&15))*128 + nidx]);
        #pragma unroll
        for(int g3=0; g3<3; g3++) xr[r][g3] = xg[xb[r] + g3*128];
      }
      hreg[r] = h0;
      hl[0][row*136 + nidx] = f2b(h0);
    }

    int cur = 0;
    for(int i=0; i<maxlen; i++){
      // prefetch next step's 12 values into registers
      unsigned short xn[4][3];
      #pragma unroll
      for(int r=0; r<4; r++){
        if(i+1 < rl[r]){
          size_t base = xb[r] + (size_t)(i+1)*384;
          #pragma unroll
          for(int g3=0; g3<3; g3++) xn[r][g3] = xg[base + g3*128];
        }
      }
      __syncthreads();                           // hl[cur] (h_i) complete
      short8 af[4];
      #pragma unroll
      for(int ks=0; ks<4; ks++)
        af[ks] = *(const short8*)&hl[cur][col*136 + ks*32 + quad*8];
      f32x4 ar = {bhv[0], bhv[0], bhv[0], bhv[0]};
      f32x4 az = {bhv[1], bhv[1], bhv[1], bhv[1]};
      f32x4 an = {bhv[2], bhv[2], bhv[2], bhv[2]};
      #pragma unroll
      for(int ks=0; ks<4; ks++){
        ar = MFMA16(af[ks], whf[0][ks], ar);
        az = MFMA16(af[ks], whf[1][ks], az);
        an = MFMA16(af[ks], whf[2][ks], an);
      }
      #pragma unroll
      for(int r=0; r<4; r++){
        int row = quad*4 + r;
        float xrv = b2f(xr[r][0]);
        float xzv = b2f(xr[r][1]);
        float xnv = b2f(xr[r][2]);
        float rr = sigm(xrv + ar[r]);
        float zz = sigm(xzv + az[r]);
        float nn = tanh_fast(xnv + rr*an[r]);
        float hnew = (1.f - zz)*nn + zz*hreg[r];
        if(i < rl[r]){
          int b = srb[row], t = srt[row] + i;
          ys[((size_t)(t*8 + (b>>4))*16 + (b&15))*128 + nidx] = f2b(hnew);
          if(i == rl[r]-1 && (srt[row] + rl[r]) == T_SZ)
            hT[b*128 + nidx] = hnew;
        }
        hreg[r] = hnew;
        hl[cur^1][row*136 + nidx] = f2b(hnew);   // h_{i+1} into other buffer
        if(i+1 < rl[r]){
          xr[r][0] = xn[r][0]; xr[r][1] = xn[r][1]; xr[r][2] = xn[r][2];
        }
      }
      cur ^= 1;
    }
  }
}

// ---------------------------------------------------------------------------
// K3: out = y @ W_out.T + b_out.
// ---------------------------------------------------------------------------
__global__ __launch_bounds__(256) void out_gemm(
    const unsigned short* __restrict__ ys,
    const float* __restrict__ Wout, const float* __restrict__ bout,
    float* __restrict__ outp)
{
  const int tid = threadIdx.x;
  const int wv = tid >> 6, l = tid & 63, quad = l >> 4, col = l & 15;
  const int n = 16*wv + col;
  short8 wof[4];
  #pragma unroll
  for(int ks=0; ks<4; ks++) wof[ks] = load_w8(Wout + n*128 + ks*32 + quad*8);
  const float bov = bout[n];
  for(int tile = blockIdx.x; tile < 8192; tile += gridDim.x){
    const int t = tile >> 3, g = tile & 7;
    const unsigned short* yt = ys + (size_t)tile * 16 * 128;
    f32x4 acc = {bov, bov, bov, bov};
    #pragma unroll
    for(int ks=0; ks<4; ks++){
      short8 a = *(const short8*)&yt[col*128 + ks*32 + quad*8];
      acc = MFMA16(a, wof[ks], acc);
    }
    #pragma unroll
    for(int r=0; r<4; r++)
      outp[(size_t)(16*g + quad*4 + r)*(T_SZ*64) + (size_t)t*64 + n] = acc[r];
  }
}

extern "C" void kernel_launch(void* const* d_in, const int* in_sizes, int n_in,
                              void* d_out, int out_size, void* d_ws, size_t ws_size,
                              hipStream_t stream)
{
  const float* x    = (const float*)d_in[0];
  const int*   ii   = (const int*)  d_in[1];
  const float* hx   = (const float*)d_in[2];
  const float* W1   = (const float*)d_in[3];
  const float* b1   = (const float*)d_in[4];
  const float* W2   = (const float*)d_in[5];
  const float* b2   = (const float*)d_in[6];
  const float* Wih  = (const float*)d_in[7];
  const float* bih  = (const float*)d_in[8];
  const float* Whh  = (const float*)d_in[9];
  const float* bhh  = (const float*)d_in[10];
  const float* Wout = (const float*)d_in[11];
  const float* bout = (const float*)d_in[12];

  float* outp = (float*)d_out;
  float* hT   = outp + (size_t)128 * T_SZ * 64;
  uint32* C   = (uint32*)d_out;

  unsigned short* xg = (unsigned short*)d_ws;                          // 100,663,296 B
  unsigned short* ys = (unsigned short*)((char*)d_ws + 100663296ull);  //  33,554,432 B

  hipMemsetAsync(C, 0, 64, stream);
  seg_build  <<<dim3(16),   dim3(512),  0, stream>>>(ii, C);
  fused_mlp  <<<dim3(512),  dim3(512),  0, stream>>>(x, ii, W1, b1, W2, b2, Wih, bih, bhh, xg, ys, hT);
  gru_seg_scan<<<dim3(2048),dim3(512),  0, stream>>>(xg, hx, Whh, bhh, C, ys, hT);
  out_gemm   <<<dim3(2048), dim3(256),  0, stream>>>(ys, Wout, bout, outp);
}

// Round 7
// 309.359 us; speedup vs baseline: 1.0388x; 1.0388x over previous
//
#include <hip/hip_runtime.h>

// GRUModule: MLP(64->128->128,ELU) -> xg=W_ih proj -> segment-parallel GRU(H=128) -> W_out head
// B=128, T=1024. All GEMMs via mfma_f32_16x16x32_bf16.
// ws: [xg bf16 [b][t][384]: 100,663,296 B][ys bf16 [t][g][16][128]: 33,554,432 B] = 128 MiB
// ctrl+segs live in d_out (first ~540 KB), overwritten by out_gemm afterwards.
// R7: scan reverted to R5 wide cooperative staging (u64/lane, 256B chunks) —
//     R6's 12 narrow scattered loads/step regressed. hl AND xbuf double-buffered
//     -> 1 barrier/step. Grid 2048->512: ~4 tiles/block amortize the 96-float4
//     Whh fragment setup (was the dominant per-block cost).

#define T_SZ 1024

typedef __attribute__((ext_vector_type(8))) short short8;
typedef __attribute__((ext_vector_type(4))) float f32x4;
typedef unsigned long long u64;
typedef unsigned int uint32;

__device__ __forceinline__ unsigned short f2b(float f){
  unsigned int u = __builtin_bit_cast(unsigned int, f);
  u += 0x7fffu + ((u >> 16) & 1u);
  return (unsigned short)(u >> 16);
}
__device__ __forceinline__ float b2f(unsigned int hs){
  unsigned int u = hs << 16;
  return __builtin_bit_cast(float, u);
}
__device__ __forceinline__ short8 load_w8(const float* __restrict__ p){
  const float4* q = (const float4*)p;
  float4 u0 = q[0], u1 = q[1];
  short8 v;
  v[0]=(short)f2b(u0.x); v[1]=(short)f2b(u0.y); v[2]=(short)f2b(u0.z); v[3]=(short)f2b(u0.w);
  v[4]=(short)f2b(u1.x); v[5]=(short)f2b(u1.y); v[6]=(short)f2b(u1.z); v[7]=(short)f2b(u1.w);
  return v;
}
__device__ __forceinline__ float elu(float v){ return v > 0.f ? v : __expf(v) - 1.f; }
__device__ __forceinline__ float sigm(float x){ return 1.f / (1.f + __expf(-x)); }
__device__ __forceinline__ float tanh_fast(float x){
  x = fminf(fmaxf(x, -15.f), 15.f);
  float e = __expf(-2.f * x);
  return (1.f - e) / (1.f + e);
}
#define MFMA16(a,b,c) __builtin_amdgcn_mfma_f32_16x16x32_bf16(a, b, c, 0, 0, 0)

// ctrl layout in d_out (as uint32*): [1]=n_tiles [2]=slot cursor; segs = C+4096

// ---------------------------------------------------------------------------
// seg_build: 16 blocks x 512 thr; block owns 8 batch rows. Enumerate reset-
// delimited segments; reset-started segments are shortened by 1 (step 0 is
// handled elementwise in fused_mlp); counting-sort desc-by-length in LDS;
// reserve 16-aligned global region with ONE atomicAdd; write + len-0 padding.
// ---------------------------------------------------------------------------
__global__ __launch_bounds__(512) void seg_build(const int* __restrict__ ii, uint32* C){
  __shared__ uint32 lh[1024];
  __shared__ uint32 lbase[1024];
  __shared__ uint32 ssum[512];
  __shared__ uint32 sbase;
  uint32* segs = C + 4096;
  const int tid = threadIdx.x;
  const int wv = tid >> 6, lane = tid & 63;
  const int b = blockIdx.x*8 + wv;

  for(int i = tid; i < 1024; i += 512) lh[i] = 0u;
  __syncthreads();

  u64 bal[16], mb[16];
  #pragma unroll
  for(int c=0;c<16;c++){
    int t = c*64 + lane;
    int m = ii[b*T_SZ + t];
    mb[c]  = __ballot(m != 0);
    bal[c] = __ballot((m != 0) || (t == 0));
  }
  int fsA[16]; int nx = T_SZ;
  #pragma unroll
  for(int c=15;c>=0;c--){ fsA[c]=nx; if(bal[c]) nx = c*64 + __builtin_ctzll(bal[c]); }

  int lenA[16], tA[16], rkA[16];
  #pragma unroll
  for(int c=0;c<16;c++){
    lenA[c] = 0;
    if((bal[c] >> lane) & 1ull){
      int t = c*64 + lane;
      u64 hi = (lane < 63) ? (bal[c] >> (lane+1)) : 0ull;
      int nxt = hi ? (t + 1 + __builtin_ctzll(hi)) : fsA[c];
      int len = nxt - t;
      int rst = (int)((mb[c] >> lane) & 1ull);
      len -= rst; t += rst;
      if(len > 0){
        lenA[c] = len; tA[c] = t;
        rkA[c] = (int)atomicAdd(&lh[1024 - len], 1u);
      }
    }
  }
  __syncthreads();

  uint32 c0 = lh[2*tid], c1 = lh[2*tid+1];
  ssum[tid] = c0 + c1;
  __syncthreads();
  #pragma unroll
  for(int off=1; off<512; off<<=1){
    uint32 v = (tid >= off) ? ssum[tid-off] : 0u;
    __syncthreads();
    ssum[tid] += v;
    __syncthreads();
  }
  uint32 excl = tid ? ssum[tid-1] : 0u;
  lbase[2*tid]   = excl;
  lbase[2*tid+1] = excl + c0;
  uint32 total = ssum[511];
  uint32 padded = (total + 15u) & ~15u;
  if(tid == 0){
    sbase = atomicAdd(&C[2], padded);
    atomicAdd(&C[1], padded >> 4);
  }
  __syncthreads();
  const uint32 base = sbase;

  #pragma unroll
  for(int c=0;c<16;c++){
    if(lenA[c] > 0){
      uint32 slot = base + lbase[1024 - lenA[c]] + (uint32)rkA[c];
      segs[slot] = ((uint32)b << 21) | ((uint32)tA[c] << 11) | (uint32)lenA[c];
    }
  }
  for(uint32 i = total + tid; i < padded; i += 512) segs[base + i] = 0u;
}

// ---------------------------------------------------------------------------
// K1: fused MLP1 + MLP2 + W_ih + elementwise reset-step. M=64 tile
// (16 b x 4 t). 8 waves, wave wv owns N-slice n=16wv+col.
// ---------------------------------------------------------------------------
__global__ __launch_bounds__(512) void fused_mlp(
    const float* __restrict__ x, const int* __restrict__ ii,
    const float* __restrict__ W1, const float* __restrict__ b1,
    const float* __restrict__ W2, const float* __restrict__ b2,
    const float* __restrict__ Wih, const float* __restrict__ bih,
    const float* __restrict__ bhh,
    unsigned short* __restrict__ xg, unsigned short* __restrict__ ys,
    float* __restrict__ hT)
{
  __shared__ __align__(16) char smem[53248];
  unsigned short* xs  = (unsigned short*)smem;            // [4][16][72] = 18432 B
  unsigned short* h1l = (unsigned short*)(smem + 18432);  // [4][16][136] = 17408 B
  unsigned short* h2l = (unsigned short*)(smem + 35840);  // [4][16][136] = 17408 B
  unsigned short* xgl = (unsigned short*)smem;            // [16][388] = 12416 B (overlay)
  __shared__ int iil[64];
  const int tid = threadIdx.x;
  const int wv = tid >> 6, l = tid & 63, quad = l >> 4, col = l & 15;
  const int n = 16*wv + col;

  short8 w1f[2], w2f[4], wif[3][4];
  #pragma unroll
  for(int ks=0; ks<2; ks++) w1f[ks] = load_w8(W1 + n*64  + ks*32 + quad*8);
  #pragma unroll
  for(int ks=0; ks<4; ks++) w2f[ks] = load_w8(W2 + n*128 + ks*32 + quad*8);
  #pragma unroll
  for(int gt=0; gt<3; gt++){
    #pragma unroll
    for(int ks=0; ks<4; ks++)
      wif[gt][ks] = load_w8(Wih + (n + 128*gt)*128 + ks*32 + quad*8);
  }
  const float b1v = b1[n], b2v = b2[n];
  float bihv[3], bhhv[3];
  #pragma unroll
  for(int gt=0; gt<3; gt++){ bihv[gt] = bih[n + 128*gt]; bhhv[gt] = bhh[n + 128*gt]; }

  const int srow = tid >> 5, sk = tid & 31;

  for(int tile = blockIdx.x; tile < 2048; tile += gridDim.x){
    const int g = tile & 7, t0 = (tile >> 3) * 4;
    __syncthreads();
    {
      const float* src = x + (size_t)(16*g + srow)*(T_SZ*64) + (size_t)t0*64;
      #pragma unroll
      for(int j=0; j<2; j++){
        int s = sk + 32*j;
        float4 v = ((const float4*)src)[s];
        int tt = s >> 4, k = (s & 15) * 4;
        unsigned short* dst = xs + (tt*16 + srow)*72 + k;
        dst[0]=f2b(v.x); dst[1]=f2b(v.y); dst[2]=f2b(v.z); dst[3]=f2b(v.w);
      }
    }
    if(tid < 64) iil[tid] = ii[(16*g + (tid & 15))*T_SZ + t0 + (tid >> 4)];
    __syncthreads();
    #pragma unroll
    for(int tt=0; tt<4; tt++){
      f32x4 acc = {b1v, b1v, b1v, b1v};
      #pragma unroll
      for(int ks=0; ks<2; ks++){
        short8 a = *(const short8*)&xs[(tt*16 + col)*72 + ks*32 + quad*8];
        acc = MFMA16(a, w1f[ks], acc);
      }
      #pragma unroll
      for(int r=0; r<4; r++)
        h1l[(tt*16 + quad*4 + r)*136 + n] = f2b(elu(acc[r]));
    }
    __syncthreads();
    #pragma unroll
    for(int tt=0; tt<4; tt++){
      f32x4 acc = {b2v, b2v, b2v, b2v};
      #pragma unroll
      for(int ks=0; ks<4; ks++){
        short8 a = *(const short8*)&h1l[(tt*16 + col)*136 + ks*32 + quad*8];
        acc = MFMA16(a, w2f[ks], acc);
      }
      #pragma unroll
      for(int r=0; r<4; r++)
        h2l[(tt*16 + quad*4 + r)*136 + n] = f2b(elu(acc[r]));
    }
    __syncthreads();
    #pragma unroll
    for(int tt=0; tt<4; tt++){
      f32x4 a0 = {bihv[0], bihv[0], bihv[0], bihv[0]};
      f32x4 a1 = {bihv[1], bihv[1], bihv[1], bihv[1]};
      f32x4 a2 = {bihv[2], bihv[2], bihv[2], bihv[2]};
      #pragma unroll
      for(int ks=0; ks<4; ks++){
        short8 a = *(const short8*)&h2l[(tt*16 + col)*136 + ks*32 + quad*8];
        a0 = MFMA16(a, wif[0][ks], a0);
        a1 = MFMA16(a, wif[1][ks], a1);
        a2 = MFMA16(a, wif[2][ks], a2);
      }
      const int t = t0 + tt;
      #pragma unroll
      for(int r=0; r<4; r++){
        int row = quad*4 + r;
        xgl[row*388 +       n] = f2b(a0[r]);
        xgl[row*388 + 128 + n] = f2b(a1[r]);
        xgl[row*388 + 256 + n] = f2b(a2[r]);
        if(iil[tt*16 + row] != 0){
          float rr = sigm(a0[r] + bhhv[0]);
          float zz = sigm(a1[r] + bhhv[1]);
          float nn = tanh_fast(a2[r] + rr*bhhv[2]);
          float h1 = (1.f - zz)*nn;
          ys[((size_t)(t*8 + g)*16 + row)*128 + n] = f2b(h1);
          if(t == T_SZ-1)
            hT[(16*g + row)*128 + n] = h1;
        }
      }
      __syncthreads();
      {
        unsigned short* dst = xg + ((size_t)(16*g + srow)*T_SZ + t)*384;
        const unsigned short* srcl = xgl + srow*388;
        #pragma unroll
        for(int i=0; i<3; i++)
          *(u64*)(dst + i*128 + sk*4) = *(const u64*)(srcl + i*128 + sk*4);
      }
      if(tt < 3) __syncthreads();
    }
  }
}

// ---------------------------------------------------------------------------
// K2 v4: segment-parallel GRU. One block = tile of 16 segments. Wide
// cooperative xg staging (u64/lane, 256B chunks) into double-buffered xbuf;
// hl double-buffered too -> ONE barrier/step. Grid 512: ~4 tiles/block
// amortize the Whh-fragment setup.
// ---------------------------------------------------------------------------
__global__ __launch_bounds__(512) void gru_seg_scan(
    const unsigned short* __restrict__ xg,
    const float* __restrict__ hx,
    const float* __restrict__ Whh, const float* __restrict__ bhh,
    const uint32* __restrict__ C,
    unsigned short* __restrict__ ys, float* __restrict__ hT)
{
  __shared__ unsigned short hl[2][16*136];       // 2 x 4352 B
  __shared__ unsigned short xbuf[2][16*772];     // 2 x 24704 B
  __shared__ int srb[16], srt[16], srlen[16];
  const int tid = threadIdx.x;
  const int wv = tid >> 6, l = tid & 63, quad = l >> 4, col = l & 15;
  const int nidx = 16*wv + col;
  const int frow = tid >> 5, fk = tid & 31;

  const uint32 ntile = C[1];
  const uint32* segs = C + 4096;

  short8 whf[3][4];
  float bhv[3];
  #pragma unroll
  for(int gt=0; gt<3; gt++){
    int n = nidx + 128*gt;
    bhv[gt] = bhh[n];
    #pragma unroll
    for(int ks=0; ks<4; ks++)
      whf[gt][ks] = load_w8(Whh + n*128 + ks*32 + quad*8);
  }

  for(uint32 tile = blockIdx.x; tile < ntile; tile += gridDim.x){
    __syncthreads();                             // prev tile fully done
    if(tid < 16){
      uint32 w = segs[16*tile + (uint32)tid];
      srb[tid] = (int)(w >> 21);
      srt[tid] = (int)((w >> 11) & 1023u);
      srlen[tid] = (int)(w & 2047u);
    }
    __syncthreads();
    const int maxlen = srlen[0];

    float hreg[4];
    int rl[4];
    #pragma unroll
    for(int r=0; r<4; r++){
      int row = quad*4 + r;
      int b = srb[row], t0 = srt[row];
      rl[r] = srlen[row];
      float h0 = 0.f;
      if(rl[r] > 0){
        h0 = (t0 == 0) ? hx[b*128 + nidx]
                       : b2f(ys[((size_t)((t0-1)*8 + (b>>4))*16 + (b&15))*128 + nidx]);
      }
      hreg[r] = h0;
      hl[0][row*136 + nidx] = f2b(h0);
    }
    // prologue: step-0 xg rows into xbuf[0] (wide cooperative staging)
    {
      const unsigned short* src = xg + ((size_t)srb[frow]*T_SZ + srt[frow])*384;
      unsigned short* xb = &xbuf[0][frow*772];
      #pragma unroll
      for(int i=0; i<3; i++)
        *(u64*)(xb + i*128 + fk*4) = *(const u64*)(src + i*128 + fk*4);
    }

    int cur = 0;
    for(int i=0; i<maxlen; i++){
      // prefetch step i+1 (clamped) into registers, wide
      u64 p0, p1, p2;
      {
        int rf = srlen[frow];
        int tc = (i+1 < rf) ? i+1 : (rf > 0 ? rf-1 : 0);
        const unsigned short* src = xg + ((size_t)srb[frow]*T_SZ + (srt[frow] + tc))*384;
        p0 = *(const u64*)(src +       fk*4);
        p1 = *(const u64*)(src + 128 + fk*4);
        p2 = *(const u64*)(src + 256 + fk*4);
      }
      __syncthreads();                           // hl[cur] h_i + xbuf[cur] ready
      short8 af[4];
      #pragma unroll
      for(int ks=0; ks<4; ks++)
        af[ks] = *(const short8*)&hl[cur][col*136 + ks*32 + quad*8];
      f32x4 ar = {bhv[0], bhv[0], bhv[0], bhv[0]};
      f32x4 az = {bhv[1], bhv[1], bhv[1], bhv[1]};
      f32x4 an = {bhv[2], bhv[2], bhv[2], bhv[2]};
      #pragma unroll
      for(int ks=0; ks<4; ks++){
        ar = MFMA16(af[ks], whf[0][ks], ar);
        az = MFMA16(af[ks], whf[1][ks], az);
        an = MFMA16(af[ks], whf[2][ks], an);
      }
      const unsigned short* xb = &xbuf[cur][0];
      #pragma unroll
      for(int r=0; r<4; r++){
        int row = quad*4 + r;
        float xrv = b2f(xb[row*772 +       nidx]);
        float xzv = b2f(xb[row*772 + 128 + nidx]);
        float xnv = b2f(xb[row*772 + 256 + nidx]);
        float rr = sigm(xrv + ar[r]);
        float zz = sigm(xzv + az[r]);
        float nn = tanh_fast(xnv + rr*an[r]);
        float hnew = (1.f - zz)*nn + zz*hreg[r];
        if(i < rl[r]){
          int b = srb[row], t = srt[row] + i;
          ys[((size_t)(t*8 + (b>>4))*16 + (b&15))*128 + nidx] = f2b(hnew);
          if(i == rl[r]-1 && (srt[row] + rl[r]) == T_SZ)
            hT[b*128 + nidx] = hnew;
        }
        hreg[r] = hnew;
        hl[cur^1][row*136 + nidx] = f2b(hnew);   // h_{i+1} -> other buffer
      }
      // drain prefetch into the other xbuf (consumed after next barrier)
      {
        unsigned short* xb2 = &xbuf[cur^1][frow*772];
        *(u64*)(xb2 +       fk*4) = p0;
        *(u64*)(xb2 + 128 + fk*4) = p1;
        *(u64*)(xb2 + 256 + fk*4) = p2;
      }
      cur ^= 1;
    }
  }
}

// ---------------------------------------------------------------------------
// K3: out = y @ W_out.T + b_out.
// ---------------------------------------------------------------------------
__global__ __launch_bounds__(256) void out_gemm(
    const unsigned short* __restrict__ ys,
    const float* __restrict__ Wout, const float* __restrict__ bout,
    float* __restrict__ outp)
{
  const int tid = threadIdx.x;
  const int wv = tid >> 6, l = tid & 63, quad = l >> 4, col = l & 15;
  const int n = 16*wv + col;
  short8 wof[4];
  #pragma unroll
  for(int ks=0; ks<4; ks++) wof[ks] = load_w8(Wout + n*128 + ks*32 + quad*8);
  const float bov = bout[n];
  for(int tile = blockIdx.x; tile < 8192; tile += gridDim.x){
    const int t = tile >> 3, g = tile & 7;
    const unsigned short* yt = ys + (size_t)tile * 16 * 128;
    f32x4 acc = {bov, bov, bov, bov};
    #pragma unroll
    for(int ks=0; ks<4; ks++){
      short8 a = *(const short8*)&yt[col*128 + ks*32 + quad*8];
      acc = MFMA16(a, wof[ks], acc);
    }
    #pragma unroll
    for(int r=0; r<4; r++)
      outp[(size_t)(16*g + quad*4 + r)*(T_SZ*64) + (size_t)t*64 + n] = acc[r];
  }
}

extern "C" void kernel_launch(void* const* d_in, const int* in_sizes, int n_in,
                              void* d_out, int out_size, void* d_ws, size_t ws_size,
                              hipStream_t stream)
{
  const float* x    = (const float*)d_in[0];
  const int*   ii   = (const int*)  d_in[1];
  const float* hx   = (const float*)d_in[2];
  const float* W1   = (const float*)d_in[3];
  const float* b1   = (const float*)d_in[4];
  const float* W2   = (const float*)d_in[5];
  const float* b2   = (const float*)d_in[6];
  const float* Wih  = (const float*)d_in[7];
  const float* bih  = (const float*)d_in[8];
  const float* Whh  = (const float*)d_in[9];
  const float* bhh  = (const float*)d_in[10];
  const float* Wout = (const float*)d_in[11];
  const float* bout = (const float*)d_in[12];

  float* outp = (float*)d_out;
  float* hT   = outp + (size_t)128 * T_SZ * 64;
  uint32* C   = (uint32*)d_out;

  unsigned short* xg = (unsigned short*)d_ws;                          // 100,663,296 B
  unsigned short* ys = (unsigned short*)((char*)d_ws + 100663296ull);  //  33,554,432 B

  hipMemsetAsync(C, 0, 64, stream);
  seg_build  <<<dim3(16),   dim3(512),  0, stream>>>(ii, C);
  fused_mlp  <<<dim3(512),  dim3(512),  0, stream>>>(x, ii, W1, b1, W2, b2, Wih, bih, bhh, xg, ys, hT);
  gru_seg_scan<<<dim3(512), dim3(512),  0, stream>>>(xg, hx, Whh, bhh, C, ys, hT);
  out_gemm   <<<dim3(2048), dim3(256),  0, stream>>>(ys, Wout, bout, outp);
}

// Round 8
// 295.916 us; speedup vs baseline: 1.0860x; 1.0454x over previous
//
#include <hip/hip_runtime.h>

// GRUModule: MLP(64->128->128,ELU) -> xg=W_ih proj -> segment-parallel GRU(H=128) -> W_out head
// B=128, T=1024. All GEMMs via mfma_f32_16x16x32_bf16.
// ws: [xg bf16 [b][t][384]: 100,663,296 B][ys bf16 [t][g][16][128]: 33,554,432 B] = 128 MiB
// ctrl+segs live in d_out (first ~540 KB), overwritten by out_gemm afterwards.
// R8: scan loop ROTATED — barrier at top; global prefetch issued mid-body so
//     MFMA+gates (~500 cyc) cover the pre-barrier vmcnt(0) drain (was: issue
//     -> barrier -> full latency exposed every step). ys writes now cooperative
//     coalesced u64 (1/thread) one step delayed from hl[cur]; gates are pure
//     VALU+LDS. Grid 512->1024 shortens worst-block serial chain.

#define T_SZ 1024

typedef __attribute__((ext_vector_type(8))) short short8;
typedef __attribute__((ext_vector_type(4))) float f32x4;
typedef unsigned long long u64;
typedef unsigned int uint32;

__device__ __forceinline__ unsigned short f2b(float f){
  unsigned int u = __builtin_bit_cast(unsigned int, f);
  u += 0x7fffu + ((u >> 16) & 1u);
  return (unsigned short)(u >> 16);
}
__device__ __forceinline__ float b2f(unsigned int hs){
  unsigned int u = hs << 16;
  return __builtin_bit_cast(float, u);
}
__device__ __forceinline__ short8 load_w8(const float* __restrict__ p){
  const float4* q = (const float4*)p;
  float4 u0 = q[0], u1 = q[1];
  short8 v;
  v[0]=(short)f2b(u0.x); v[1]=(short)f2b(u0.y); v[2]=(short)f2b(u0.z); v[3]=(short)f2b(u0.w);
  v[4]=(short)f2b(u1.x); v[5]=(short)f2b(u1.y); v[6]=(short)f2b(u1.z); v[7]=(short)f2b(u1.w);
  return v;
}
__device__ __forceinline__ float elu(float v){ return v > 0.f ? v : __expf(v) - 1.f; }
__device__ __forceinline__ float sigm(float x){ return 1.f / (1.f + __expf(-x)); }
__device__ __forceinline__ float tanh_fast(float x){
  x = fminf(fmaxf(x, -15.f), 15.f);
  float e = __expf(-2.f * x);
  return (1.f - e) / (1.f + e);
}
#define MFMA16(a,b,c) __builtin_amdgcn_mfma_f32_16x16x32_bf16(a, b, c, 0, 0, 0)

// ctrl layout in d_out (as uint32*): [1]=n_tiles [2]=slot cursor; segs = C+4096

// ---------------------------------------------------------------------------
// seg_build: 16 blocks x 512 thr; block owns 8 batch rows. Enumerate reset-
// delimited segments; reset-started segments are shortened by 1 (step 0 is
// handled elementwise in fused_mlp); counting-sort desc-by-length in LDS;
// reserve 16-aligned global region with ONE atomicAdd; write + len-0 padding.
// ---------------------------------------------------------------------------
__global__ __launch_bounds__(512) void seg_build(const int* __restrict__ ii, uint32* C){
  __shared__ uint32 lh[1024];
  __shared__ uint32 lbase[1024];
  __shared__ uint32 ssum[512];
  __shared__ uint32 sbase;
  uint32* segs = C + 4096;
  const int tid = threadIdx.x;
  const int wv = tid >> 6, lane = tid & 63;
  const int b = blockIdx.x*8 + wv;

  for(int i = tid; i < 1024; i += 512) lh[i] = 0u;
  __syncthreads();

  u64 bal[16], mb[16];
  #pragma unroll
  for(int c=0;c<16;c++){
    int t = c*64 + lane;
    int m = ii[b*T_SZ + t];
    mb[c]  = __ballot(m != 0);
    bal[c] = __ballot((m != 0) || (t == 0));
  }
  int fsA[16]; int nx = T_SZ;
  #pragma unroll
  for(int c=15;c>=0;c--){ fsA[c]=nx; if(bal[c]) nx = c*64 + __builtin_ctzll(bal[c]); }

  int lenA[16], tA[16], rkA[16];
  #pragma unroll
  for(int c=0;c<16;c++){
    lenA[c] = 0;
    if((bal[c] >> lane) & 1ull){
      int t = c*64 + lane;
      u64 hi = (lane < 63) ? (bal[c] >> (lane+1)) : 0ull;
      int nxt = hi ? (t + 1 + __builtin_ctzll(hi)) : fsA[c];
      int len = nxt - t;
      int rst = (int)((mb[c] >> lane) & 1ull);
      len -= rst; t += rst;
      if(len > 0){
        lenA[c] = len; tA[c] = t;
        rkA[c] = (int)atomicAdd(&lh[1024 - len], 1u);
      }
    }
  }
  __syncthreads();

  uint32 c0 = lh[2*tid], c1 = lh[2*tid+1];
  ssum[tid] = c0 + c1;
  __syncthreads();
  #pragma unroll
  for(int off=1; off<512; off<<=1){
    uint32 v = (tid >= off) ? ssum[tid-off] : 0u;
    __syncthreads();
    ssum[tid] += v;
    __syncthreads();
  }
  uint32 excl = tid ? ssum[tid-1] : 0u;
  lbase[2*tid]   = excl;
  lbase[2*tid+1] = excl + c0;
  uint32 total = ssum[511];
  uint32 padded = (total + 15u) & ~15u;
  if(tid == 0){
    sbase = atomicAdd(&C[2], padded);
    atomicAdd(&C[1], padded >> 4);
  }
  __syncthreads();
  const uint32 base = sbase;

  #pragma unroll
  for(int c=0;c<16;c++){
    if(lenA[c] > 0){
      uint32 slot = base + lbase[1024 - lenA[c]] + (uint32)rkA[c];
      segs[slot] = ((uint32)b << 21) | ((uint32)tA[c] << 11) | (uint32)lenA[c];
    }
  }
  for(uint32 i = total + tid; i < padded; i += 512) segs[base + i] = 0u;
}

// ---------------------------------------------------------------------------
// K1: fused MLP1 + MLP2 + W_ih + elementwise reset-step. M=64 tile
// (16 b x 4 t). 8 waves, wave wv owns N-slice n=16wv+col.
// ---------------------------------------------------------------------------
__global__ __launch_bounds__(512) void fused_mlp(
    const float* __restrict__ x, const int* __restrict__ ii,
    const float* __restrict__ W1, const float* __restrict__ b1,
    const float* __restrict__ W2, const float* __restrict__ b2,
    const float* __restrict__ Wih, const float* __restrict__ bih,
    const float* __restrict__ bhh,
    unsigned short* __restrict__ xg, unsigned short* __restrict__ ys,
    float* __restrict__ hT)
{
  __shared__ __align__(16) char smem[53248];
  unsigned short* xs  = (unsigned short*)smem;            // [4][16][72] = 18432 B
  unsigned short* h1l = (unsigned short*)(smem + 18432);  // [4][16][136] = 17408 B
  unsigned short* h2l = (unsigned short*)(smem + 35840);  // [4][16][136] = 17408 B
  unsigned short* xgl = (unsigned short*)smem;            // [16][388] = 12416 B (overlay)
  __shared__ int iil[64];
  const int tid = threadIdx.x;
  const int wv = tid >> 6, l = tid & 63, quad = l >> 4, col = l & 15;
  const int n = 16*wv + col;

  short8 w1f[2], w2f[4], wif[3][4];
  #pragma unroll
  for(int ks=0; ks<2; ks++) w1f[ks] = load_w8(W1 + n*64  + ks*32 + quad*8);
  #pragma unroll
  for(int ks=0; ks<4; ks++) w2f[ks] = load_w8(W2 + n*128 + ks*32 + quad*8);
  #pragma unroll
  for(int gt=0; gt<3; gt++){
    #pragma unroll
    for(int ks=0; ks<4; ks++)
      wif[gt][ks] = load_w8(Wih + (n + 128*gt)*128 + ks*32 + quad*8);
  }
  const float b1v = b1[n], b2v = b2[n];
  float bihv[3], bhhv[3];
  #pragma unroll
  for(int gt=0; gt<3; gt++){ bihv[gt] = bih[n + 128*gt]; bhhv[gt] = bhh[n + 128*gt]; }

  const int srow = tid >> 5, sk = tid & 31;

  for(int tile = blockIdx.x; tile < 2048; tile += gridDim.x){
    const int g = tile & 7, t0 = (tile >> 3) * 4;
    __syncthreads();
    {
      const float* src = x + (size_t)(16*g + srow)*(T_SZ*64) + (size_t)t0*64;
      #pragma unroll
      for(int j=0; j<2; j++){
        int s = sk + 32*j;
        float4 v = ((const float4*)src)[s];
        int tt = s >> 4, k = (s & 15) * 4;
        unsigned short* dst = xs + (tt*16 + srow)*72 + k;
        dst[0]=f2b(v.x); dst[1]=f2b(v.y); dst[2]=f2b(v.z); dst[3]=f2b(v.w);
      }
    }
    if(tid < 64) iil[tid] = ii[(16*g + (tid & 15))*T_SZ + t0 + (tid >> 4)];
    __syncthreads();
    #pragma unroll
    for(int tt=0; tt<4; tt++){
      f32x4 acc = {b1v, b1v, b1v, b1v};
      #pragma unroll
      for(int ks=0; ks<2; ks++){
        short8 a = *(const short8*)&xs[(tt*16 + col)*72 + ks*32 + quad*8];
        acc = MFMA16(a, w1f[ks], acc);
      }
      #pragma unroll
      for(int r=0; r<4; r++)
        h1l[(tt*16 + quad*4 + r)*136 + n] = f2b(elu(acc[r]));
    }
    __syncthreads();
    #pragma unroll
    for(int tt=0; tt<4; tt++){
      f32x4 acc = {b2v, b2v, b2v, b2v};
      #pragma unroll
      for(int ks=0; ks<4; ks++){
        short8 a = *(const short8*)&h1l[(tt*16 + col)*136 + ks*32 + quad*8];
        acc = MFMA16(a, w2f[ks], acc);
      }
      #pragma unroll
      for(int r=0; r<4; r++)
        h2l[(tt*16 + quad*4 + r)*136 + n] = f2b(elu(acc[r]));
    }
    __syncthreads();
    #pragma unroll
    for(int tt=0; tt<4; tt++){
      f32x4 a0 = {bihv[0], bihv[0], bihv[0], bihv[0]};
      f32x4 a1 = {bihv[1], bihv[1], bihv[1], bihv[1]};
      f32x4 a2 = {bihv[2], bihv[2], bihv[2], bihv[2]};
      #pragma unroll
      for(int ks=0; ks<4; ks++){
        short8 a = *(const short8*)&h2l[(tt*16 + col)*136 + ks*32 + quad*8];
        a0 = MFMA16(a, wif[0][ks], a0);
        a1 = MFMA16(a, wif[1][ks], a1);
        a2 = MFMA16(a, wif[2][ks], a2);
      }
      const int t = t0 + tt;
      #pragma unroll
      for(int r=0; r<4; r++){
        int row = quad*4 + r;
        xgl[row*388 +       n] = f2b(a0[r]);
        xgl[row*388 + 128 + n] = f2b(a1[r]);
        xgl[row*388 + 256 + n] = f2b(a2[r]);
        if(iil[tt*16 + row] != 0){
          float rr = sigm(a0[r] + bhhv[0]);
          float zz = sigm(a1[r] + bhhv[1]);
          float nn = tanh_fast(a2[r] + rr*bhhv[2]);
          float h1 = (1.f - zz)*nn;
          ys[((size_t)(t*8 + g)*16 + row)*128 + n] = f2b(h1);
          if(t == T_SZ-1)
            hT[(16*g + row)*128 + n] = h1;
        }
      }
      __syncthreads();
      {
        unsigned short* dst = xg + ((size_t)(16*g + srow)*T_SZ + t)*384;
        const unsigned short* srcl = xgl + srow*388;
        #pragma unroll
        for(int i=0; i<3; i++)
          *(u64*)(dst + i*128 + sk*4) = *(const u64*)(srcl + i*128 + sk*4);
      }
      if(tt < 3) __syncthreads();
    }
  }
}

// ---------------------------------------------------------------------------
// K2 v5: segment-parallel GRU, drain-aware. One block = tile of 16 segments.
// Barrier at TOP of step loop; global prefetch issued mid-body (covered by
// MFMA+gates before the next drain). ys written cooperatively (coalesced u64,
// one step delayed, from hl[cur]); final step flushed after the loop.
// ---------------------------------------------------------------------------
__global__ __launch_bounds__(512) void gru_seg_scan(
    const unsigned short* __restrict__ xg,
    const float* __restrict__ hx,
    const float* __restrict__ Whh, const float* __restrict__ bhh,
    const uint32* __restrict__ C,
    unsigned short* __restrict__ ys, float* __restrict__ hT)
{
  __shared__ unsigned short hl[2][16*136];       // 2 x 4352 B
  __shared__ unsigned short xbuf[2][16*772];     // 2 x 24704 B
  __shared__ int srb[16], srt[16], srlen[16];
  const int tid = threadIdx.x;
  const int wv = tid >> 6, l = tid & 63, quad = l >> 4, col = l & 15;
  const int nidx = 16*wv + col;
  const int frow = tid >> 5, fk = tid & 31;

  const uint32 ntile = C[1];
  const uint32* segs = C + 4096;

  short8 whf[3][4];
  float bhv[3];
  #pragma unroll
  for(int gt=0; gt<3; gt++){
    int n = nidx + 128*gt;
    bhv[gt] = bhh[n];
    #pragma unroll
    for(int ks=0; ks<4; ks++)
      whf[gt][ks] = load_w8(Whh + n*128 + ks*32 + quad*8);
  }

  for(uint32 tile = blockIdx.x; tile < ntile; tile += gridDim.x){
    __syncthreads();                             // prev tile fully done
    if(tid < 16){
      uint32 w = segs[16*tile + (uint32)tid];
      srb[tid] = (int)(w >> 21);
      srt[tid] = (int)((w >> 11) & 1023u);
      srlen[tid] = (int)(w & 2047u);
    }
    __syncthreads();
    const int maxlen = srlen[0];
    // per-frow segment info for the cooperative fetch/store lanes
    const int fb = srb[frow], ft = srt[frow], fl = srlen[frow];

    float hreg[4];
    #pragma unroll
    for(int r=0; r<4; r++){
      int row = quad*4 + r;
      int b = srb[row], t0 = srt[row];
      float h0 = 0.f;
      if(srlen[row] > 0){
        h0 = (t0 == 0) ? hx[b*128 + nidx]
                       : b2f(ys[((size_t)((t0-1)*8 + (b>>4))*16 + (b&15))*128 + nidx]);
      }
      hreg[r] = h0;
      hl[0][row*136 + nidx] = f2b(h0);
    }
    // prologue: step-0 xg rows into xbuf[0] (wide cooperative staging)
    {
      const unsigned short* src = xg + ((size_t)fb*T_SZ + ft)*384;
      unsigned short* xb = &xbuf[0][frow*772];
      #pragma unroll
      for(int i2=0; i2<3; i2++)
        *(u64*)(xb + i2*128 + fk*4) = *(const u64*)(src + i2*128 + fk*4);
    }

    int cur = 0;
    for(int i=0; i<maxlen; i++){
      __syncthreads();                 // hl[cur]=h_i, xbuf[cur]=xg_i visible
      // A-frag reads + MFMA issue FIRST
      short8 af[4];
      #pragma unroll
      for(int ks=0; ks<4; ks++)
        af[ks] = *(const short8*)&hl[cur][col*136 + ks*32 + quad*8];
      f32x4 ar = {bhv[0], bhv[0], bhv[0], bhv[0]};
      f32x4 az = {bhv[1], bhv[1], bhv[1], bhv[1]};
      f32x4 an = {bhv[2], bhv[2], bhv[2], bhv[2]};
      #pragma unroll
      for(int ks=0; ks<4; ks++){
        ar = MFMA16(af[ks], whf[0][ks], ar);
        az = MFMA16(af[ks], whf[1][ks], az);
        an = MFMA16(af[ks], whf[2][ks], an);
      }
      // prefetch step i+1 (clamped): issued with MFMA+gates still ahead of the
      // next barrier's vmcnt(0) drain
      u64 p0, p1, p2;
      {
        int tc = (i+1 < fl) ? i+1 : (fl > 0 ? fl-1 : 0);
        const unsigned short* src = xg + ((size_t)fb*T_SZ + (ft + tc))*384;
        p0 = *(const u64*)(src +       fk*4);
        p1 = *(const u64*)(src + 128 + fk*4);
        p2 = *(const u64*)(src + 256 + fk*4);
      }
      // cooperative coalesced ys write of step i-1 from hl[cur]
      if(i >= 1 && i <= fl){
        int t = ft + i - 1;
        u64 hv = *(const u64*)&hl[cur][frow*136 + fk*4];
        *(u64*)(ys + ((size_t)(t*8 + (fb>>4))*16 + (fb&15))*128 + fk*4) = hv;
        if(i == fl && ft + fl == T_SZ){
          #pragma unroll
          for(int j=0; j<4; j++)
            hT[fb*128 + fk*4 + j] = b2f(hl[cur][frow*136 + fk*4 + j]);
        }
      }
      // gates: pure VALU + LDS
      const unsigned short* xb = &xbuf[cur][0];
      #pragma unroll
      for(int r=0; r<4; r++){
        int row = quad*4 + r;
        float xrv = b2f(xb[row*772 +       nidx]);
        float xzv = b2f(xb[row*772 + 128 + nidx]);
        float xnv = b2f(xb[row*772 + 256 + nidx]);
        float rr = sigm(xrv + ar[r]);
        float zz = sigm(xzv + az[r]);
        float nn = tanh_fast(xnv + rr*an[r]);
        float hnew = (1.f - zz)*nn + zz*hreg[r];
        hreg[r] = hnew;
        hl[cur^1][row*136 + nidx] = f2b(hnew);   // h_{i+1} -> other buffer
      }
      // drain prefetch into the other xbuf (consumed after next top barrier)
      {
        unsigned short* xb2 = &xbuf[cur^1][frow*772];
        *(u64*)(xb2 +       fk*4) = p0;
        *(u64*)(xb2 + 128 + fk*4) = p1;
        *(u64*)(xb2 + 256 + fk*4) = p2;
      }
      cur ^= 1;
    }
    // flush final step's h (rows with full length)
    __syncthreads();
    if(maxlen >= 1 && fl == maxlen){
      int t = ft + maxlen - 1;
      u64 hv = *(const u64*)&hl[cur][frow*136 + fk*4];
      *(u64*)(ys + ((size_t)(t*8 + (fb>>4))*16 + (fb&15))*128 + fk*4) = hv;
      if(ft + fl == T_SZ){
        #pragma unroll
        for(int j=0; j<4; j++)
          hT[fb*128 + fk*4 + j] = b2f(hl[cur][frow*136 + fk*4 + j]);
      }
    }
  }
}

// ---------------------------------------------------------------------------
// K3: out = y @ W_out.T + b_out.
// ---------------------------------------------------------------------------
__global__ __launch_bounds__(256) void out_gemm(
    const unsigned short* __restrict__ ys,
    const float* __restrict__ Wout, const float* __restrict__ bout,
    float* __restrict__ outp)
{
  const int tid = threadIdx.x;
  const int wv = tid >> 6, l = tid & 63, quad = l >> 4, col = l & 15;
  const int n = 16*wv + col;
  short8 wof[4];
  #pragma unroll
  for(int ks=0; ks<4; ks++) wof[ks] = load_w8(Wout + n*128 + ks*32 + quad*8);
  const float bov = bout[n];
  for(int tile = blockIdx.x; tile < 8192; tile += gridDim.x){
    const int t = tile >> 3, g = tile & 7;
    const unsigned short* yt = ys + (size_t)tile * 16 * 128;
    f32x4 acc = {bov, bov, bov, bov};
    #pragma unroll
    for(int ks=0; ks<4; ks++){
      short8 a = *(const short8*)&yt[col*128 + ks*32 + quad*8];
      acc = MFMA16(a, wof[ks], acc);
    }
    #pragma unroll
    for(int r=0; r<4; r++)
      outp[(size_t)(16*g + quad*4 + r)*(T_SZ*64) + (size_t)t*64 + n] = acc[r];
  }
}

extern "C" void kernel_launch(void* const* d_in, const int* in_sizes, int n_in,
                              void* d_out, int out_size, void* d_ws, size_t ws_size,
                              hipStream_t stream)
{
  const float* x    = (const float*)d_in[0];
  const int*   ii   = (const int*)  d_in[1];
  const float* hx   = (const float*)d_in[2];
  const float* W1   = (const float*)d_in[3];
  const float* b1   = (const float*)d_in[4];
  const float* W2   = (const float*)d_in[5];
  const float* b2   = (const float*)d_in[6];
  const float* Wih  = (const float*)d_in[7];
  const float* bih  = (const float*)d_in[8];
  const float* Whh  = (const float*)d_in[9];
  const float* bhh  = (const float*)d_in[10];
  const float* Wout = (const float*)d_in[11];
  const float* bout = (const float*)d_in[12];

  float* outp = (float*)d_out;
  float* hT   = outp + (size_t)128 * T_SZ * 64;
  uint32* C   = (uint32*)d_out;

  unsigned short* xg = (unsigned short*)d_ws;                          // 100,663,296 B
  unsigned short* ys = (unsigned short*)((char*)d_ws + 100663296ull);  //  33,554,432 B

  hipMemsetAsync(C, 0, 64, stream);
  seg_build  <<<dim3(16),   dim3(512),  0, stream>>>(ii, C);
  fused_mlp  <<<dim3(512),  dim3(512),  0, stream>>>(x, ii, W1, b1, W2, b2, Wih, bih, bhh, xg, ys, hT);
  gru_seg_scan<<<dim3(1024),dim3(512),  0, stream>>>(xg, hx, Whh, bhh, C, ys, hT);
  out_gemm   <<<dim3(2048), dim3(256),  0, stream>>>(ys, Wout, bout, outp);
}

// Round 9
// 258.556 us; speedup vs baseline: 1.2429x; 1.1445x over previous
//
#include <hip/hip_runtime.h>

// GRUModule: MLP(64->128->128,ELU) -> xg=W_ih proj -> segment-parallel GRU(H=128) -> W_out head
// B=128, T=1024. All GEMMs via mfma_f32_16x16x32_bf16.
// ws: [xg bf16 [b][t][384]: 100,663,296 B][ys bf16 [t][g][16][128]: 33,554,432 B] = 128 MiB
// ctrl+segs in d_out[0..540KB); wbf (bf16-swizzled Whh frags, 96KB) at d_out+1MiB.
// Both are dead space until out_gemm overwrites; rewritten every call.
// R9: (1) wprep pre-swizzles Whh to bf16 frag records -> scan setup is 12
//     dwordx4 loads, no f2b VALU (was ~5us-equiv across 1024 blocks).
//     (2) scan grid 4160, ONE tile per block + early exit: the 16 long
//     run-head tiles get dedicated blocks (grid-stride had 8 blocks owning
//     two ~25-step tiles serially -> tail halves).

#define T_SZ 1024

typedef __attribute__((ext_vector_type(8))) short short8;
typedef __attribute__((ext_vector_type(4))) float f32x4;
typedef unsigned long long u64;
typedef unsigned int uint32;

__device__ __forceinline__ unsigned short f2b(float f){
  unsigned int u = __builtin_bit_cast(unsigned int, f);
  u += 0x7fffu + ((u >> 16) & 1u);
  return (unsigned short)(u >> 16);
}
__device__ __forceinline__ float b2f(unsigned int hs){
  unsigned int u = hs << 16;
  return __builtin_bit_cast(float, u);
}
__device__ __forceinline__ short8 load_w8(const float* __restrict__ p){
  const float4* q = (const float4*)p;
  float4 u0 = q[0], u1 = q[1];
  short8 v;
  v[0]=(short)f2b(u0.x); v[1]=(short)f2b(u0.y); v[2]=(short)f2b(u0.z); v[3]=(short)f2b(u0.w);
  v[4]=(short)f2b(u1.x); v[5]=(short)f2b(u1.y); v[6]=(short)f2b(u1.z); v[7]=(short)f2b(u1.w);
  return v;
}
__device__ __forceinline__ float elu(float v){ return v > 0.f ? v : __expf(v) - 1.f; }
__device__ __forceinline__ float sigm(float x){ return 1.f / (1.f + __expf(-x)); }
__device__ __forceinline__ float tanh_fast(float x){
  x = fminf(fmaxf(x, -15.f), 15.f);
  float e = __expf(-2.f * x);
  return (1.f - e) / (1.f + e);
}
#define MFMA16(a,b,c) __builtin_amdgcn_mfma_f32_16x16x32_bf16(a, b, c, 0, 0, 0)

// ctrl layout in d_out (as uint32*): [1]=n_tiles [2]=slot cursor; segs = C+4096
// wbf at d_out byte offset 1 MiB: 6144 x 16B records, rec = ((gt*4+ks)*128+n)*4+quad

// ---------------------------------------------------------------------------
// wprep: Whh fp32 -> bf16 frag-swizzled records.
// ---------------------------------------------------------------------------
__global__ __launch_bounds__(512) void wprep(const float* __restrict__ Whh, uint4* __restrict__ wbf){
  int rec = blockIdx.x*512 + threadIdx.x;
  if(rec >= 6144) return;
  int q  = rec & 3;
  int n_ = (rec >> 2) & 127;
  int ks = (rec >> 9) & 3;
  int gt = rec >> 11;
  const float* p = Whh + (size_t)(n_ + 128*gt)*128 + ks*32 + q*8;
  uint4 o;
  o.x = (uint32)f2b(p[0]) | ((uint32)f2b(p[1]) << 16);
  o.y = (uint32)f2b(p[2]) | ((uint32)f2b(p[3]) << 16);
  o.z = (uint32)f2b(p[4]) | ((uint32)f2b(p[5]) << 16);
  o.w = (uint32)f2b(p[6]) | ((uint32)f2b(p[7]) << 16);
  wbf[rec] = o;
}

// ---------------------------------------------------------------------------
// seg_build: 16 blocks x 512 thr; block owns 8 batch rows. Enumerate reset-
// delimited segments; reset-started segments are shortened by 1 (step 0 is
// handled elementwise in fused_mlp); counting-sort desc-by-length in LDS;
// reserve 16-aligned global region with ONE atomicAdd; write + len-0 padding.
// ---------------------------------------------------------------------------
__global__ __launch_bounds__(512) void seg_build(const int* __restrict__ ii, uint32* C){
  __shared__ uint32 lh[1024];
  __shared__ uint32 lbase[1024];
  __shared__ uint32 ssum[512];
  __shared__ uint32 sbase;
  uint32* segs = C + 4096;
  const int tid = threadIdx.x;
  const int wv = tid >> 6, lane = tid & 63;
  const int b = blockIdx.x*8 + wv;

  for(int i = tid; i < 1024; i += 512) lh[i] = 0u;
  __syncthreads();

  u64 bal[16], mb[16];
  #pragma unroll
  for(int c=0;c<16;c++){
    int t = c*64 + lane;
    int m = ii[b*T_SZ + t];
    mb[c]  = __ballot(m != 0);
    bal[c] = __ballot((m != 0) || (t == 0));
  }
  int fsA[16]; int nx = T_SZ;
  #pragma unroll
  for(int c=15;c>=0;c--){ fsA[c]=nx; if(bal[c]) nx = c*64 + __builtin_ctzll(bal[c]); }

  int lenA[16], tA[16], rkA[16];
  #pragma unroll
  for(int c=0;c<16;c++){
    lenA[c] = 0;
    if((bal[c] >> lane) & 1ull){
      int t = c*64 + lane;
      u64 hi = (lane < 63) ? (bal[c] >> (lane+1)) : 0ull;
      int nxt = hi ? (t + 1 + __builtin_ctzll(hi)) : fsA[c];
      int len = nxt - t;
      int rst = (int)((mb[c] >> lane) & 1ull);
      len -= rst; t += rst;
      if(len > 0){
        lenA[c] = len; tA[c] = t;
        rkA[c] = (int)atomicAdd(&lh[1024 - len], 1u);
      }
    }
  }
  __syncthreads();

  uint32 c0 = lh[2*tid], c1 = lh[2*tid+1];
  ssum[tid] = c0 + c1;
  __syncthreads();
  #pragma unroll
  for(int off=1; off<512; off<<=1){
    uint32 v = (tid >= off) ? ssum[tid-off] : 0u;
    __syncthreads();
    ssum[tid] += v;
    __syncthreads();
  }
  uint32 excl = tid ? ssum[tid-1] : 0u;
  lbase[2*tid]   = excl;
  lbase[2*tid+1] = excl + c0;
  uint32 total = ssum[511];
  uint32 padded = (total + 15u) & ~15u;
  if(tid == 0){
    sbase = atomicAdd(&C[2], padded);
    atomicAdd(&C[1], padded >> 4);
  }
  __syncthreads();
  const uint32 base = sbase;

  #pragma unroll
  for(int c=0;c<16;c++){
    if(lenA[c] > 0){
      uint32 slot = base + lbase[1024 - lenA[c]] + (uint32)rkA[c];
      segs[slot] = ((uint32)b << 21) | ((uint32)tA[c] << 11) | (uint32)lenA[c];
    }
  }
  for(uint32 i = total + tid; i < padded; i += 512) segs[base + i] = 0u;
}

// ---------------------------------------------------------------------------
// K1: fused MLP1 + MLP2 + W_ih + elementwise reset-step. M=64 tile
// (16 b x 4 t). 8 waves, wave wv owns N-slice n=16wv+col.
// ---------------------------------------------------------------------------
__global__ __launch_bounds__(512) void fused_mlp(
    const float* __restrict__ x, const int* __restrict__ ii,
    const float* __restrict__ W1, const float* __restrict__ b1,
    const float* __restrict__ W2, const float* __restrict__ b2,
    const float* __restrict__ Wih, const float* __restrict__ bih,
    const float* __restrict__ bhh,
    unsigned short* __restrict__ xg, unsigned short* __restrict__ ys,
    float* __restrict__ hT)
{
  __shared__ __align__(16) char smem[53248];
  unsigned short* xs  = (unsigned short*)smem;            // [4][16][72] = 18432 B
  unsigned short* h1l = (unsigned short*)(smem + 18432);  // [4][16][136] = 17408 B
  unsigned short* h2l = (unsigned short*)(smem + 35840);  // [4][16][136] = 17408 B
  unsigned short* xgl = (unsigned short*)smem;            // [16][388] = 12416 B (overlay)
  __shared__ int iil[64];
  const int tid = threadIdx.x;
  const int wv = tid >> 6, l = tid & 63, quad = l >> 4, col = l & 15;
  const int n = 16*wv + col;

  short8 w1f[2], w2f[4], wif[3][4];
  #pragma unroll
  for(int ks=0; ks<2; ks++) w1f[ks] = load_w8(W1 + n*64  + ks*32 + quad*8);
  #pragma unroll
  for(int ks=0; ks<4; ks++) w2f[ks] = load_w8(W2 + n*128 + ks*32 + quad*8);
  #pragma unroll
  for(int gt=0; gt<3; gt++){
    #pragma unroll
    for(int ks=0; ks<4; ks++)
      wif[gt][ks] = load_w8(Wih + (n + 128*gt)*128 + ks*32 + quad*8);
  }
  const float b1v = b1[n], b2v = b2[n];
  float bihv[3], bhhv[3];
  #pragma unroll
  for(int gt=0; gt<3; gt++){ bihv[gt] = bih[n + 128*gt]; bhhv[gt] = bhh[n + 128*gt]; }

  const int srow = tid >> 5, sk = tid & 31;

  for(int tile = blockIdx.x; tile < 2048; tile += gridDim.x){
    const int g = tile & 7, t0 = (tile >> 3) * 4;
    __syncthreads();
    {
      const float* src = x + (size_t)(16*g + srow)*(T_SZ*64) + (size_t)t0*64;
      #pragma unroll
      for(int j=0; j<2; j++){
        int s = sk + 32*j;
        float4 v = ((const float4*)src)[s];
        int tt = s >> 4, k = (s & 15) * 4;
        unsigned short* dst = xs + (tt*16 + srow)*72 + k;
        dst[0]=f2b(v.x); dst[1]=f2b(v.y); dst[2]=f2b(v.z); dst[3]=f2b(v.w);
      }
    }
    if(tid < 64) iil[tid] = ii[(16*g + (tid & 15))*T_SZ + t0 + (tid >> 4)];
    __syncthreads();
    #pragma unroll
    for(int tt=0; tt<4; tt++){
      f32x4 acc = {b1v, b1v, b1v, b1v};
      #pragma unroll
      for(int ks=0; ks<2; ks++){
        short8 a = *(const short8*)&xs[(tt*16 + col)*72 + ks*32 + quad*8];
        acc = MFMA16(a, w1f[ks], acc);
      }
      #pragma unroll
      for(int r=0; r<4; r++)
        h1l[(tt*16 + quad*4 + r)*136 + n] = f2b(elu(acc[r]));
    }
    __syncthreads();
    #pragma unroll
    for(int tt=0; tt<4; tt++){
      f32x4 acc = {b2v, b2v, b2v, b2v};
      #pragma unroll
      for(int ks=0; ks<4; ks++){
        short8 a = *(const short8*)&h1l[(tt*16 + col)*136 + ks*32 + quad*8];
        acc = MFMA16(a, w2f[ks], acc);
      }
      #pragma unroll
      for(int r=0; r<4; r++)
        h2l[(tt*16 + quad*4 + r)*136 + n] = f2b(elu(acc[r]));
    }
    __syncthreads();
    #pragma unroll
    for(int tt=0; tt<4; tt++){
      f32x4 a0 = {bihv[0], bihv[0], bihv[0], bihv[0]};
      f32x4 a1 = {bihv[1], bihv[1], bihv[1], bihv[1]};
      f32x4 a2 = {bihv[2], bihv[2], bihv[2], bihv[2]};
      #pragma unroll
      for(int ks=0; ks<4; ks++){
        short8 a = *(const short8*)&h2l[(tt*16 + col)*136 + ks*32 + quad*8];
        a0 = MFMA16(a, wif[0][ks], a0);
        a1 = MFMA16(a, wif[1][ks], a1);
        a2 = MFMA16(a, wif[2][ks], a2);
      }
      const int t = t0 + tt;
      #pragma unroll
      for(int r=0; r<4; r++){
        int row = quad*4 + r;
        xgl[row*388 +       n] = f2b(a0[r]);
        xgl[row*388 + 128 + n] = f2b(a1[r]);
        xgl[row*388 + 256 + n] = f2b(a2[r]);
        if(iil[tt*16 + row] != 0){
          float rr = sigm(a0[r] + bhhv[0]);
          float zz = sigm(a1[r] + bhhv[1]);
          float nn = tanh_fast(a2[r] + rr*bhhv[2]);
          float h1 = (1.f - zz)*nn;
          ys[((size_t)(t*8 + g)*16 + row)*128 + n] = f2b(h1);
          if(t == T_SZ-1)
            hT[(16*g + row)*128 + n] = h1;
        }
      }
      __syncthreads();
      {
        unsigned short* dst = xg + ((size_t)(16*g + srow)*T_SZ + t)*384;
        const unsigned short* srcl = xgl + srow*388;
        #pragma unroll
        for(int i=0; i<3; i++)
          *(u64*)(dst + i*128 + sk*4) = *(const u64*)(srcl + i*128 + sk*4);
      }
      if(tt < 3) __syncthreads();
    }
  }
}

// ---------------------------------------------------------------------------
// K2 v6: segment-parallel GRU, drain-aware. ONE tile per block (grid 4160,
// early-exit past ntile). Whh frags loaded pre-swizzled from wbf (dwordx4,
// no conversion VALU). Barrier at top of step loop; prefetch mid-body;
// ys cooperative coalesced u64, one step delayed.
// ---------------------------------------------------------------------------
__global__ __launch_bounds__(512) void gru_seg_scan(
    const unsigned short* __restrict__ xg,
    const float* __restrict__ hx,
    const uint4* __restrict__ wbf, const float* __restrict__ bhh,
    const uint32* __restrict__ C,
    unsigned short* __restrict__ ys, float* __restrict__ hT)
{
  __shared__ unsigned short hl[2][16*136];       // 2 x 4352 B
  __shared__ unsigned short xbuf[2][16*772];     // 2 x 24704 B
  __shared__ int srb[16], srt[16], srlen[16];
  const uint32 ntile = C[1];
  const uint32 tile = blockIdx.x;
  if(tile >= ntile) return;

  const int tid = threadIdx.x;
  const int wv = tid >> 6, l = tid & 63, quad = l >> 4, col = l & 15;
  const int nidx = 16*wv + col;
  const int frow = tid >> 5, fk = tid & 31;
  const uint32* segs = C + 4096;

  short8 whf[3][4];
  float bhv[3];
  #pragma unroll
  for(int gt=0; gt<3; gt++){
    bhv[gt] = bhh[nidx + 128*gt];
    #pragma unroll
    for(int ks=0; ks<4; ks++){
      uint4 w = wbf[((gt*4 + ks)*128 + nidx)*4 + quad];
      whf[gt][ks] = __builtin_bit_cast(short8, w);
    }
  }

  if(tid < 16){
    uint32 w = segs[16*tile + (uint32)tid];
    srb[tid] = (int)(w >> 21);
    srt[tid] = (int)((w >> 11) & 1023u);
    srlen[tid] = (int)(w & 2047u);
  }
  __syncthreads();
  const int maxlen = srlen[0];
  const int fb = srb[frow], ft = srt[frow], fl = srlen[frow];

  float hreg[4];
  #pragma unroll
  for(int r=0; r<4; r++){
    int row = quad*4 + r;
    int b = srb[row], t0 = srt[row];
    float h0 = 0.f;
    if(srlen[row] > 0){
      h0 = (t0 == 0) ? hx[b*128 + nidx]
                     : b2f(ys[((size_t)((t0-1)*8 + (b>>4))*16 + (b&15))*128 + nidx]);
    }
    hreg[r] = h0;
    hl[0][row*136 + nidx] = f2b(h0);
  }
  // prologue: step-0 xg rows into xbuf[0]
  {
    const unsigned short* src = xg + ((size_t)fb*T_SZ + ft)*384;
    unsigned short* xb = &xbuf[0][frow*772];
    #pragma unroll
    for(int i2=0; i2<3; i2++)
      *(u64*)(xb + i2*128 + fk*4) = *(const u64*)(src + i2*128 + fk*4);
  }

  int cur = 0;
  for(int i=0; i<maxlen; i++){
    __syncthreads();                 // hl[cur]=h_i, xbuf[cur]=xg_i visible
    short8 af[4];
    #pragma unroll
    for(int ks=0; ks<4; ks++)
      af[ks] = *(const short8*)&hl[cur][col*136 + ks*32 + quad*8];
    f32x4 ar = {bhv[0], bhv[0], bhv[0], bhv[0]};
    f32x4 az = {bhv[1], bhv[1], bhv[1], bhv[1]};
    f32x4 an = {bhv[2], bhv[2], bhv[2], bhv[2]};
    #pragma unroll
    for(int ks=0; ks<4; ks++){
      ar = MFMA16(af[ks], whf[0][ks], ar);
      az = MFMA16(af[ks], whf[1][ks], az);
      an = MFMA16(af[ks], whf[2][ks], an);
    }
    // prefetch step i+1 (clamped): covered by MFMA+gates before next drain
    u64 p0, p1, p2;
    {
      int tc = (i+1 < fl) ? i+1 : (fl > 0 ? fl-1 : 0);
      const unsigned short* src = xg + ((size_t)fb*T_SZ + (ft + tc))*384;
      p0 = *(const u64*)(src +       fk*4);
      p1 = *(const u64*)(src + 128 + fk*4);
      p2 = *(const u64*)(src + 256 + fk*4);
    }
    // cooperative coalesced ys write of step i-1 from hl[cur]
    if(i >= 1 && i <= fl){
      int t = ft + i - 1;
      u64 hv = *(const u64*)&hl[cur][frow*136 + fk*4];
      *(u64*)(ys + ((size_t)(t*8 + (fb>>4))*16 + (fb&15))*128 + fk*4) = hv;
      if(i == fl && ft + fl == T_SZ){
        #pragma unroll
        for(int j=0; j<4; j++)
          hT[fb*128 + fk*4 + j] = b2f(hl[cur][frow*136 + fk*4 + j]);
      }
    }
    // gates
    const unsigned short* xb = &xbuf[cur][0];
    #pragma unroll
    for(int r=0; r<4; r++){
      int row = quad*4 + r;
      float xrv = b2f(xb[row*772 +       nidx]);
      float xzv = b2f(xb[row*772 + 128 + nidx]);
      float xnv = b2f(xb[row*772 + 256 + nidx]);
      float rr = sigm(xrv + ar[r]);
      float zz = sigm(xzv + az[r]);
      float nn = tanh_fast(xnv + rr*an[r]);
      float hnew = (1.f - zz)*nn + zz*hreg[r];
      hreg[r] = hnew;
      hl[cur^1][row*136 + nidx] = f2b(hnew);
    }
    {
      unsigned short* xb2 = &xbuf[cur^1][frow*772];
      *(u64*)(xb2 +       fk*4) = p0;
      *(u64*)(xb2 + 128 + fk*4) = p1;
      *(u64*)(xb2 + 256 + fk*4) = p2;
    }
    cur ^= 1;
  }
  // flush final step
  __syncthreads();
  if(maxlen >= 1 && fl == maxlen){
    int t = ft + maxlen - 1;
    u64 hv = *(const u64*)&hl[cur][frow*136 + fk*4];
    *(u64*)(ys + ((size_t)(t*8 + (fb>>4))*16 + (fb&15))*128 + fk*4) = hv;
    if(ft + fl == T_SZ){
      #pragma unroll
      for(int j=0; j<4; j++)
        hT[fb*128 + fk*4 + j] = b2f(hl[cur][frow*136 + fk*4 + j]);
    }
  }
}

// ---------------------------------------------------------------------------
// K3: out = y @ W_out.T + b_out.
// ---------------------------------------------------------------------------
__global__ __launch_bounds__(256) void out_gemm(
    const unsigned short* __restrict__ ys,
    const float* __restrict__ Wout, const float* __restrict__ bout,
    float* __restrict__ outp)
{
  const int tid = threadIdx.x;
  const int wv = tid >> 6, l = tid & 63, quad = l >> 4, col = l & 15;
  const int n = 16*wv + col;
  short8 wof[4];
  #pragma unroll
  for(int ks=0; ks<4; ks++) wof[ks] = load_w8(Wout + n*128 + ks*32 + quad*8);
  const float bov = bout[n];
  for(int tile = blockIdx.x; tile < 8192; tile += gridDim.x){
    const int t = tile >> 3, g = tile & 7;
    const unsigned short* yt = ys + (size_t)tile * 16 * 128;
    f32x4 acc = {bov, bov, bov, bov};
    #pragma unroll
    for(int ks=0; ks<4; ks++){
      short8 a = *(const short8*)&yt[col*128 + ks*32 + quad*8];
      acc = MFMA16(a, wof[ks], acc);
    }
    #pragma unroll
    for(int r=0; r<4; r++)
      outp[(size_t)(16*g + quad*4 + r)*(T_SZ*64) + (size_t)t*64 + n] = acc[r];
  }
}

extern "C" void kernel_launch(void* const* d_in, const int* in_sizes, int n_in,
                              void* d_out, int out_size, void* d_ws, size_t ws_size,
                              hipStream_t stream)
{
  const float* x    = (const float*)d_in[0];
  const int*   ii   = (const int*)  d_in[1];
  const float* hx   = (const float*)d_in[2];
  const float* W1   = (const float*)d_in[3];
  const float* b1   = (const float*)d_in[4];
  const float* W2   = (const float*)d_in[5];
  const float* b2   = (const float*)d_in[6];
  const float* Wih  = (const float*)d_in[7];
  const float* bih  = (const float*)d_in[8];
  const float* Whh  = (const float*)d_in[9];
  const float* bhh  = (const float*)d_in[10];
  const float* Wout = (const float*)d_in[11];
  const float* bout = (const float*)d_in[12];

  float* outp = (float*)d_out;
  float* hT   = outp + (size_t)128 * T_SZ * 64;
  uint32* C   = (uint32*)d_out;
  uint4* wbf  = (uint4*)((char*)d_out + (1u<<20));   // 96KB at +1MiB, dead until out_gemm

  unsigned short* xg = (unsigned short*)d_ws;                          // 100,663,296 B
  unsigned short* ys = (unsigned short*)((char*)d_ws + 100663296ull);  //  33,554,432 B

  hipMemsetAsync(C, 0, 64, stream);
  wprep      <<<dim3(12),   dim3(512),  0, stream>>>(Whh, wbf);
  seg_build  <<<dim3(16),   dim3(512),  0, stream>>>(ii, C);
  fused_mlp  <<<dim3(512),  dim3(512),  0, stream>>>(x, ii, W1, b1, W2, b2, Wih, bih, bhh, xg, ys, hT);
  gru_seg_scan<<<dim3(4160),dim3(512),  0, stream>>>(xg, hx, wbf, bhh, C, ys, hT);
  out_gemm   <<<dim3(2048), dim3(256),  0, stream>>>(ys, Wout, bout, outp);
}